// Round 4
// baseline (461.167 us; speedup 1.0000x reference)
//
#include <hip/hip_runtime.h>

#define NEG 0.2f
#define EPSV 1e-16f
#define CAP1 128
#define CAP2 128

__device__ __forceinline__ float lrelu(float x) { return x > 0.f ? x : NEG * x; }

// ---------------- CSR build ----------------
__global__ void k_zero(int* __restrict__ p, int n) {
  int t = blockIdx.x * 256 + threadIdx.x;
  if (t < n) p[t] = 0;
}
__global__ void k_hist(const int* __restrict__ dst, int* __restrict__ cnt, int E) {
  int t = blockIdx.x * 256 + threadIdx.x;
  if (t < E) atomicAdd(&cnt[dst[t]], 1);
}
__global__ __launch_bounds__(1024) void k_scan1(const int* __restrict__ cnt,
                                                int* __restrict__ row_ptr,
                                                int* __restrict__ bsum, int N) {
  __shared__ int sh[1024];
  int t = blockIdx.x * 1024 + threadIdx.x;
  int v = (t < N) ? cnt[t] : 0;
  sh[threadIdx.x] = v;
  __syncthreads();
  for (int off = 1; off < 1024; off <<= 1) {
    int add = (threadIdx.x >= off) ? sh[threadIdx.x - off] : 0;
    __syncthreads();
    sh[threadIdx.x] += add;
    __syncthreads();
  }
  if (t < N) row_ptr[t] = sh[threadIdx.x] - v;
  if (threadIdx.x == 1023) bsum[blockIdx.x] = sh[1023];
}
__global__ __launch_bounds__(64) void k_scan2(int* __restrict__ bsum,
                                              int* __restrict__ row_ptr, int nb, int N) {
  int tid = threadIdx.x;
  int v = (tid < nb) ? bsum[tid] : 0;
  int inc = v;
#pragma unroll
  for (int off = 1; off < 64; off <<= 1) {
    int u = __shfl_up(inc, off);
    if (tid >= off) inc += u;
  }
  if (tid < nb) bsum[tid] = inc - v;
  if (tid == 63) row_ptr[N] = inc;
}
__global__ void k_scan3(const int* __restrict__ bsum, int* __restrict__ row_ptr,
                        int* __restrict__ cursor, int N) {
  int t = blockIdx.x * 256 + threadIdx.x;
  if (t < N) {
    int v = row_ptr[t] + bsum[t >> 10];
    row_ptr[t] = v;
    cursor[t] = v;
  }
}
__global__ void k_scatter(const int* __restrict__ src, const int* __restrict__ dst,
                          int* __restrict__ cursor, int* __restrict__ csr_src, int E) {
  int t = blockIdx.x * 256 + threadIdx.x;
  if (t >= E) return;
  int i = dst[t];
  int pos = atomicAdd(&cursor[i], 1);
  csr_src[pos] = src[t];
}

// ------- GEMM + fused attention dots: Hout = X@W ; as_/ad_ = <H, att> -------
template <int K, int M, int R, int H, int C>
__global__ __launch_bounds__(256) void k_gemm_att(const float* __restrict__ X,
                                                  const float* __restrict__ W,
                                                  const float* __restrict__ atts,
                                                  const float* __restrict__ attd,
                                                  float* __restrict__ Hout,
                                                  float* __restrict__ as_,
                                                  float* __restrict__ ad_, int N) {
  __shared__ float ws[K * M];
  __shared__ float xs[R * K];
  __shared__ float hs[R * M];
  const int tid = threadIdx.x;
  for (int idx = tid * 4; idx < K * M; idx += 1024)
    *(float4*)&ws[idx] = *(const float4*)&W[idx];
  const long row0 = (long)blockIdx.x * R;
  const int nrow = (int)min((long)R, (long)N - row0);
  for (int idx = tid * 4; idx < R * K; idx += 1024) {
    int r = idx / K;
    float4 v = make_float4(0.f, 0.f, 0.f, 0.f);
    if (r < nrow) v = *(const float4*)&X[row0 * K + idx];
    *(float4*)&xs[idx] = v;
  }
  __syncthreads();
  constexpr int NCT = M / 4;
  constexpr int RS = 256 / NCT;
  const int c0 = (tid % NCT) * 4;
  const int rslot = tid / NCT;
  for (int r = rslot; r < R; r += RS) {
    float4 acc = make_float4(0.f, 0.f, 0.f, 0.f);
#pragma unroll
    for (int k = 0; k < K; k += 4) {
      float4 xv = *(float4*)&xs[r * K + k];
      float4 w0 = *(float4*)&ws[(k + 0) * M + c0];
      float4 w1 = *(float4*)&ws[(k + 1) * M + c0];
      float4 w2 = *(float4*)&ws[(k + 2) * M + c0];
      float4 w3 = *(float4*)&ws[(k + 3) * M + c0];
      acc.x += xv.x * w0.x + xv.y * w1.x + xv.z * w2.x + xv.w * w3.x;
      acc.y += xv.x * w0.y + xv.y * w1.y + xv.z * w2.y + xv.w * w3.y;
      acc.z += xv.x * w0.z + xv.y * w1.z + xv.z * w2.z + xv.w * w3.z;
      acc.w += xv.x * w0.w + xv.y * w1.w + xv.z * w2.w + xv.w * w3.w;
    }
    *(float4*)&hs[r * M + c0] = acc;
    if (r < nrow) *(float4*)&Hout[(row0 + r) * M + c0] = acc;
  }
  __syncthreads();
  // attention dots from the LDS tile
  for (int t = tid; t < R * H; t += 256) {
    int r = t / H, h = t - r * H;
    if (r < nrow) {
      const float* hp = &hs[r * M + h * C];
      const float* sp = &atts[h * C];
      const float* dp = &attd[h * C];
      float s = 0.f, d = 0.f;
#pragma unroll
      for (int c = 0; c < C; c++) {
        float v = hp[c];
        s += v * sp[c];
        d += v * dp[c];
      }
      as_[(row0 + r) * H + h] = s;
      ad_[(row0 + r) * H + h] = d;
    }
  }
}

// ---------------- fused per-node softmax+aggregate, layer 1 (H=8,C=16) ----------------
__global__ __launch_bounds__(256) void k_node1(const int* __restrict__ row_ptr,
                                               const int* __restrict__ csr_src,
                                               const float* __restrict__ Hf,
                                               const float* __restrict__ as_,
                                               const float* __restrict__ ad_,
                                               const float* __restrict__ bias,
                                               float* __restrict__ out, int N) {
  __shared__ float pl[4][CAP1 * 8];
  __shared__ int jl[4][CAP1];
  __shared__ float sm_m[4][8], sm_r[4][8], sm_p[4][8];
  const int wid = threadIdx.x >> 6, lane = threadIdx.x & 63;
  const int i = blockIdx.x * 4 + wid;
  const bool active = i < N;
  const int ii = active ? i : (N - 1);
  const int beg = row_ptr[ii];
  const int deg = active ? (row_ptr[ii + 1] - beg) : 0;

  float4 d0 = *(const float4*)&ad_[ii * 8], d1 = *(const float4*)&ad_[ii * 8 + 4];
  float4 s0 = *(const float4*)&as_[ii * 8], s1 = *(const float4*)&as_[ii * 8 + 4];
  float adv[8] = {d0.x, d0.y, d0.z, d0.w, d1.x, d1.y, d1.z, d1.w};
  float asv[8] = {s0.x, s0.y, s0.z, s0.w, s1.x, s1.y, s1.z, s1.w};
  float aself[8], m[8];
#pragma unroll
  for (int h = 0; h < 8; h++) {
    aself[h] = lrelu(asv[h] + adv[h]);
    m[h] = aself[h];
  }
  // phase A: alphas -> LDS, running max
  for (int e = lane; e < deg; e += 64) {
    int j = csr_src[beg + e];
    float4 a0 = *(const float4*)&as_[j * 8], a1 = *(const float4*)&as_[j * 8 + 4];
    float av[8] = {a0.x, a0.y, a0.z, a0.w, a1.x, a1.y, a1.z, a1.w};
#pragma unroll
    for (int h = 0; h < 8; h++) {
      float a = lrelu(av[h] + adv[h]);
      if (e < CAP1) pl[wid][e * 8 + h] = a;
      m[h] = fmaxf(m[h], a);
    }
    if (e < CAP1) jl[wid][e] = j;
  }
#pragma unroll
  for (int h = 0; h < 8; h++)
#pragma unroll
    for (int off = 32; off > 0; off >>= 1) m[h] = fmaxf(m[h], __shfl_xor(m[h], off));
  // phase B: exp + sum
  float ss[8] = {0.f, 0.f, 0.f, 0.f, 0.f, 0.f, 0.f, 0.f};
  for (int e = lane; e < deg; e += 64) {
    if (e < CAP1) {
#pragma unroll
      for (int h = 0; h < 8; h++) {
        float p = __expf(pl[wid][e * 8 + h] - m[h]);
        pl[wid][e * 8 + h] = p;
        ss[h] += p;
      }
    } else {
      int j = csr_src[beg + e];
      float4 a0 = *(const float4*)&as_[j * 8], a1 = *(const float4*)&as_[j * 8 + 4];
      float av[8] = {a0.x, a0.y, a0.z, a0.w, a1.x, a1.y, a1.z, a1.w};
#pragma unroll
      for (int h = 0; h < 8; h++) ss[h] += __expf(lrelu(av[h] + adv[h]) - m[h]);
    }
  }
#pragma unroll
  for (int h = 0; h < 8; h++)
#pragma unroll
    for (int off = 32; off > 0; off >>= 1) ss[h] += __shfl_xor(ss[h], off);
#pragma unroll
  for (int h = 0; h < 8; h++) {
    float pself = __expf(aself[h] - m[h]);
    float rd = 1.f / (ss[h] + pself + EPSV);
    if (lane == h) {
      sm_m[wid][h] = m[h];
      sm_r[wid][h] = rd;
      sm_p[wid][h] = pself;
    }
  }
  __syncthreads();
  // phase C: half-wave per edge stream; lane owns 4 channels (float4)
  const int sub = lane >> 5, ln = lane & 31;
  const int f0 = ln * 4, hf = ln >> 2;
  const float rdh = sm_r[wid][hf], psh = sm_p[wid][hf], mh = sm_m[wid][hf];
  float4 acc = make_float4(0.f, 0.f, 0.f, 0.f);
  if (sub == 0) {
    float4 hv = *(const float4*)&Hf[(long)ii * 128 + f0];
    acc.x = psh * hv.x;
    acc.y = psh * hv.y;
    acc.z = psh * hv.z;
    acc.w = psh * hv.w;
  }
  if (deg <= CAP1) {
    int e = sub;
    for (; e + 2 < deg; e += 4) {
      int j0 = jl[wid][e], j1 = jl[wid][e + 2];
      float p0 = pl[wid][e * 8 + hf], p1 = pl[wid][(e + 2) * 8 + hf];
      float4 v0 = *(const float4*)&Hf[(long)j0 * 128 + f0];
      float4 v1 = *(const float4*)&Hf[(long)j1 * 128 + f0];
      acc.x += p0 * v0.x + p1 * v1.x;
      acc.y += p0 * v0.y + p1 * v1.y;
      acc.z += p0 * v0.z + p1 * v1.z;
      acc.w += p0 * v0.w + p1 * v1.w;
    }
    for (; e < deg; e += 2) {
      int j = jl[wid][e];
      float p = pl[wid][e * 8 + hf];
      float4 v = *(const float4*)&Hf[(long)j * 128 + f0];
      acc.x += p * v.x;
      acc.y += p * v.y;
      acc.z += p * v.z;
      acc.w += p * v.w;
    }
  } else if (sub == 0) {  // rare fallback
    for (int e = 0; e < deg; e++) {
      int j;
      float p;
      if (e < CAP1) {
        j = jl[wid][e];
        p = pl[wid][e * 8 + hf];
      } else {
        j = csr_src[beg + e];
        p = __expf(lrelu(as_[j * 8 + hf] + ad_[ii * 8 + hf]) - mh);
      }
      float4 v = *(const float4*)&Hf[(long)j * 128 + f0];
      acc.x += p * v.x;
      acc.y += p * v.y;
      acc.z += p * v.z;
      acc.w += p * v.w;
    }
  }
  acc.x += __shfl_xor(acc.x, 32);
  acc.y += __shfl_xor(acc.y, 32);
  acc.z += __shfl_xor(acc.z, 32);
  acc.w += __shfl_xor(acc.w, 32);
  if (active && sub == 0) {
    float4 b = *(const float4*)&bias[f0];
    float4 o;
    o.x = fmaxf(acc.x * rdh + b.x, 0.f);
    o.y = fmaxf(acc.y * rdh + b.y, 0.f);
    o.z = fmaxf(acc.z * rdh + b.z, 0.f);
    o.w = fmaxf(acc.w * rdh + b.w, 0.f);
    *(float4*)&out[(long)i * 128 + f0] = o;
  }
}

// ---------------- fused per-node softmax+aggregate, layer 2 (H=1,C=64) ----------------
__global__ __launch_bounds__(256) void k_node2(const int* __restrict__ row_ptr,
                                               const int* __restrict__ csr_src,
                                               const float* __restrict__ Hf,
                                               const float* __restrict__ as_,
                                               const float* __restrict__ ad_,
                                               const float* __restrict__ bias,
                                               float* __restrict__ out, int N) {
  __shared__ float pl[4][CAP2];
  __shared__ int jl[4][CAP2];
  const int wid = threadIdx.x >> 6, lane = threadIdx.x & 63;
  const int i = blockIdx.x * 4 + wid;
  const bool active = i < N;
  const int ii = active ? i : (N - 1);
  const int beg = row_ptr[ii];
  const int deg = active ? (row_ptr[ii + 1] - beg) : 0;

  const float adi = ad_[ii];
  const float aself = lrelu(as_[ii] + adi);
  float m = aself;
  for (int e = lane; e < deg; e += 64) {
    int j = csr_src[beg + e];
    float a = lrelu(as_[j] + adi);
    if (e < CAP2) {
      pl[wid][e] = a;
      jl[wid][e] = j;
    }
    m = fmaxf(m, a);
  }
#pragma unroll
  for (int off = 32; off > 0; off >>= 1) m = fmaxf(m, __shfl_xor(m, off));
  float ss = 0.f;
  for (int e = lane; e < deg; e += 64) {
    if (e < CAP2) {
      float p = __expf(pl[wid][e] - m);
      pl[wid][e] = p;
      ss += p;
    } else {
      int j = csr_src[beg + e];
      ss += __expf(lrelu(as_[j] + adi) - m);
    }
  }
#pragma unroll
  for (int off = 32; off > 0; off >>= 1) ss += __shfl_xor(ss, off);
  const float pself = __expf(aself - m);
  const float rd = 1.f / (ss + pself + EPSV);
  __syncthreads();
  // phase C: quarter-wave per edge stream; lane owns 4 channels (float4)
  const int sub = lane >> 4, ln = lane & 15;
  const int f0 = ln * 4;
  float4 acc = make_float4(0.f, 0.f, 0.f, 0.f);
  if (sub == 0) {
    float4 hv = *(const float4*)&Hf[(long)ii * 64 + f0];
    acc.x = pself * hv.x;
    acc.y = pself * hv.y;
    acc.z = pself * hv.z;
    acc.w = pself * hv.w;
  }
  if (deg <= CAP2) {
    int e = sub;
    for (; e + 4 < deg; e += 8) {
      int j0 = jl[wid][e], j1 = jl[wid][e + 4];
      float p0 = pl[wid][e], p1 = pl[wid][e + 4];
      float4 v0 = *(const float4*)&Hf[(long)j0 * 64 + f0];
      float4 v1 = *(const float4*)&Hf[(long)j1 * 64 + f0];
      acc.x += p0 * v0.x + p1 * v1.x;
      acc.y += p0 * v0.y + p1 * v1.y;
      acc.z += p0 * v0.z + p1 * v1.z;
      acc.w += p0 * v0.w + p1 * v1.w;
    }
    for (; e < deg; e += 4) {
      int j = jl[wid][e];
      float p = pl[wid][e];
      float4 v = *(const float4*)&Hf[(long)j * 64 + f0];
      acc.x += p * v.x;
      acc.y += p * v.y;
      acc.z += p * v.z;
      acc.w += p * v.w;
    }
  } else if (sub == 0) {  // rare fallback
    for (int e = 0; e < deg; e++) {
      int j;
      float p;
      if (e < CAP2) {
        j = jl[wid][e];
        p = pl[wid][e];
      } else {
        j = csr_src[beg + e];
        p = __expf(lrelu(as_[j] + adi) - m);
      }
      float4 v = *(const float4*)&Hf[(long)j * 64 + f0];
      acc.x += p * v.x;
      acc.y += p * v.y;
      acc.z += p * v.z;
      acc.w += p * v.w;
    }
  }
#pragma unroll
  for (int off = 16; off <= 32; off <<= 1) {
    acc.x += __shfl_xor(acc.x, off);
    acc.y += __shfl_xor(acc.y, off);
    acc.z += __shfl_xor(acc.z, off);
    acc.w += __shfl_xor(acc.w, off);
  }
  if (active && sub == 0) {
    float4 b = *(const float4*)&bias[f0];
    float4 o;
    o.x = acc.x * rd + b.x;
    o.y = acc.y * rd + b.y;
    o.z = acc.z * rd + b.z;
    o.w = acc.w * rd + b.w;
    *(float4*)&out[(long)i * 64 + f0] = o;
  }
}

extern "C" void kernel_launch(void* const* d_in, const int* in_sizes, int n_in,
                              void* d_out, int out_size, void* d_ws, size_t ws_size,
                              hipStream_t stream) {
  const float* x = (const float*)d_in[0];
  const int* ei = (const int*)d_in[1];
  const float* W1 = (const float*)d_in[2];
  const float* s1 = (const float*)d_in[3];
  const float* dd1 = (const float*)d_in[4];
  const float* b1 = (const float*)d_in[5];
  const float* W2 = (const float*)d_in[6];
  const float* s2 = (const float*)d_in[7];
  const float* dd2 = (const float*)d_in[8];
  const float* b2 = (const float*)d_in[9];
  const int N = in_sizes[0] / 128;
  const int E = in_sizes[1] / 2;
  const int* src = ei;
  const int* dst = ei + E;

  float* wsp = (float*)d_ws;
  float* H1 = wsp;
  float* as1 = H1 + (size_t)N * 128;
  float* ad1 = as1 + (size_t)N * 8;
  float* X2 = ad1 + (size_t)N * 8;
  int* row_ptr = (int*)(X2 + (size_t)N * 128);
  int* csr_src = row_ptr + (N + 1);
  int* bsum = csr_src + E;
  int* cursor = (int*)as1;  // alias: dead before gemm_att writes as1
  float* out = (float*)d_out;
  float* H2 = H1;
  float* as2 = as1;
  float* ad2 = ad1;

  dim3 B(256);
  auto nb = [](long n) { return dim3((unsigned)((n + 255) / 256)); };
  const int nblk = (N + 1023) / 1024;

  // CSR build (by destination)
  k_zero<<<nb(N), B, 0, stream>>>(cursor, N);
  k_hist<<<nb(E), B, 0, stream>>>(dst, cursor, E);
  k_scan1<<<dim3(nblk), dim3(1024), 0, stream>>>(cursor, row_ptr, bsum, N);
  k_scan2<<<dim3(1), dim3(64), 0, stream>>>(bsum, row_ptr, nblk, N);
  k_scan3<<<nb(N), B, 0, stream>>>(bsum, row_ptr, cursor, N);
  k_scatter<<<nb(E), B, 0, stream>>>(src, dst, cursor, csr_src, E);

  // Layer 1
  k_gemm_att<128, 128, 16, 8, 16><<<dim3((N + 15) / 16), B, 0, stream>>>(
      x, W1, s1, dd1, H1, as1, ad1, N);
  k_node1<<<dim3((N + 3) / 4), B, 0, stream>>>(row_ptr, csr_src, H1, as1, ad1, b1, X2, N);

  // Layer 2
  k_gemm_att<128, 64, 16, 1, 64><<<dim3((N + 15) / 16), B, 0, stream>>>(
      X2, W2, s2, dd2, H2, as2, ad2, N);
  k_node2<<<dim3((N + 3) / 4), B, 0, stream>>>(row_ptr, csr_src, H2, as2, ad2, b2, out, N);
}

// Round 5
// 307.169 us; speedup vs baseline: 1.5013x; 1.5013x over previous
//
#include <hip/hip_runtime.h>

#define NEG 0.2f
#define EPSV 1e-16f
#define CAP1 128
#define CAP2 128

__device__ __forceinline__ float lrelu(float x) { return x > 0.f ? x : NEG * x; }

// ---------------- CSR build ----------------
__global__ void k_zero(int* __restrict__ p, int n) {
  int t = blockIdx.x * 256 + threadIdx.x;
  if (t < n) p[t] = 0;
}
__global__ void k_hist(const int* __restrict__ dst, int* __restrict__ cnt, int E) {
  int t = blockIdx.x * 256 + threadIdx.x;
  if (t < E) atomicAdd(&cnt[dst[t]], 1);
}
__global__ __launch_bounds__(1024) void k_scan1(const int* __restrict__ cnt,
                                                int* __restrict__ row_ptr,
                                                int* __restrict__ bsum, int N) {
  __shared__ int sh[1024];
  int t = blockIdx.x * 1024 + threadIdx.x;
  int v = (t < N) ? cnt[t] : 0;
  sh[threadIdx.x] = v;
  __syncthreads();
  for (int off = 1; off < 1024; off <<= 1) {
    int add = (threadIdx.x >= off) ? sh[threadIdx.x - off] : 0;
    __syncthreads();
    sh[threadIdx.x] += add;
    __syncthreads();
  }
  if (t < N) row_ptr[t] = sh[threadIdx.x] - v;
  if (threadIdx.x == 1023) bsum[blockIdx.x] = sh[1023];
}
__global__ __launch_bounds__(64) void k_scan2(int* __restrict__ bsum,
                                              int* __restrict__ row_ptr, int nb, int N) {
  int tid = threadIdx.x;
  int v = (tid < nb) ? bsum[tid] : 0;
  int inc = v;
#pragma unroll
  for (int off = 1; off < 64; off <<= 1) {
    int u = __shfl_up(inc, off);
    if (tid >= off) inc += u;
  }
  if (tid < nb) bsum[tid] = inc - v;
  if (tid == 63) row_ptr[N] = inc;
}
__global__ void k_scan3(const int* __restrict__ bsum, int* __restrict__ row_ptr,
                        int* __restrict__ cursor, int N) {
  int t = blockIdx.x * 256 + threadIdx.x;
  if (t < N) {
    int v = row_ptr[t] + bsum[t >> 10];
    row_ptr[t] = v;
    cursor[t] = v;
  }
}
__global__ void k_scatter(const int* __restrict__ src, const int* __restrict__ dst,
                          int* __restrict__ cursor, int* __restrict__ csr_src, int E) {
  int t = blockIdx.x * 256 + threadIdx.x;
  if (t >= E) return;
  int i = dst[t];
  int pos = atomicAdd(&cursor[i], 1);
  csr_src[pos] = src[t];
}

// ---------------- GEMM: Hout[N,M] = X[N,K] @ W[K,M] ----------------
template <int K, int M, int R>
__global__ __launch_bounds__(256) void k_gemm(const float* __restrict__ X,
                                              const float* __restrict__ W,
                                              float* __restrict__ Hout, int N) {
  __shared__ float ws[K * M];
  __shared__ float xs[R * K];
  const int tid = threadIdx.x;
  for (int idx = tid * 4; idx < K * M; idx += 1024)
    *(float4*)&ws[idx] = *(const float4*)&W[idx];
  const long row0 = (long)blockIdx.x * R;
  const int nrow = (int)min((long)R, (long)N - row0);
  for (int idx = tid * 4; idx < R * K; idx += 1024) {
    int r = idx / K;
    float4 v = make_float4(0.f, 0.f, 0.f, 0.f);
    if (r < nrow) v = *(const float4*)&X[row0 * K + idx];
    *(float4*)&xs[idx] = v;
  }
  __syncthreads();
  constexpr int NCT = M / 4;
  constexpr int RS = 256 / NCT;
  const int c0 = (tid % NCT) * 4;
  const int rslot = tid / NCT;
  for (int r = rslot; r < R; r += RS) {
    float4 acc = make_float4(0.f, 0.f, 0.f, 0.f);
#pragma unroll
    for (int k = 0; k < K; k += 4) {
      float4 xv = *(float4*)&xs[r * K + k];
      float4 w0 = *(float4*)&ws[(k + 0) * M + c0];
      float4 w1 = *(float4*)&ws[(k + 1) * M + c0];
      float4 w2 = *(float4*)&ws[(k + 2) * M + c0];
      float4 w3 = *(float4*)&ws[(k + 3) * M + c0];
      acc.x += xv.x * w0.x + xv.y * w1.x + xv.z * w2.x + xv.w * w3.x;
      acc.y += xv.x * w0.y + xv.y * w1.y + xv.z * w2.y + xv.w * w3.y;
      acc.z += xv.x * w0.z + xv.y * w1.z + xv.z * w2.z + xv.w * w3.z;
      acc.w += xv.x * w0.w + xv.y * w1.w + xv.z * w2.w + xv.w * w3.w;
    }
    if (r < nrow) *(float4*)&Hout[(row0 + r) * M + c0] = acc;
  }
}

// ---------------- attention dots ----------------
template <int H, int C>
__global__ void k_att(const float* __restrict__ Hf, const float* __restrict__ atts,
                      const float* __restrict__ attd, float* __restrict__ as_,
                      float* __restrict__ ad_, int N) {
  int t = blockIdx.x * 256 + threadIdx.x;
  if (t >= N * H) return;
  int n = t / H, h = t % H;
  const float* hp = Hf + (long)n * (H * C) + h * C;
  const float* sp = atts + h * C;
  const float* dp = attd + h * C;
  float s = 0.f, d = 0.f;
#pragma unroll
  for (int c = 0; c < C; c += 4) {
    float4 hv = *(const float4*)&hp[c];
    float4 sv = *(const float4*)&sp[c];
    float4 dv = *(const float4*)&dp[c];
    s += hv.x * sv.x + hv.y * sv.y + hv.z * sv.z + hv.w * sv.w;
    d += hv.x * dv.x + hv.y * dv.y + hv.z * dv.z + hv.w * dv.w;
  }
  as_[t] = s;
  ad_[t] = d;
}

// ---------------- fused per-node softmax+aggregate, layer 1 (H=8,C=16) ----------------
__global__ __launch_bounds__(256) void k_node1(const int* __restrict__ row_ptr,
                                               const int* __restrict__ csr_src,
                                               const float* __restrict__ Hf,
                                               const float* __restrict__ as_,
                                               const float* __restrict__ ad_,
                                               const float* __restrict__ bias,
                                               float* __restrict__ out, int N) {
  __shared__ float pl[4][CAP1 * 8];
  __shared__ int jl[4][CAP1];
  __shared__ float sm_m[4][8], sm_r[4][8], sm_p[4][8];
  const int wid = threadIdx.x >> 6, lane = threadIdx.x & 63;
  const int i = blockIdx.x * 4 + wid;
  const bool active = i < N;
  const int ii = active ? i : (N - 1);
  const int beg = row_ptr[ii];
  const int deg = active ? (row_ptr[ii + 1] - beg) : 0;

  float4 d0 = *(const float4*)&ad_[ii * 8], d1 = *(const float4*)&ad_[ii * 8 + 4];
  float4 s0 = *(const float4*)&as_[ii * 8], s1 = *(const float4*)&as_[ii * 8 + 4];
  float adv[8] = {d0.x, d0.y, d0.z, d0.w, d1.x, d1.y, d1.z, d1.w};
  float asv[8] = {s0.x, s0.y, s0.z, s0.w, s1.x, s1.y, s1.z, s1.w};
  float aself[8], m[8];
#pragma unroll
  for (int h = 0; h < 8; h++) {
    aself[h] = lrelu(asv[h] + adv[h]);
    m[h] = aself[h];
  }
  // phase A: alphas -> LDS, running max
  for (int e = lane; e < deg; e += 64) {
    int j = csr_src[beg + e];
    float4 a0 = *(const float4*)&as_[j * 8], a1 = *(const float4*)&as_[j * 8 + 4];
    float av[8] = {a0.x, a0.y, a0.z, a0.w, a1.x, a1.y, a1.z, a1.w};
#pragma unroll
    for (int h = 0; h < 8; h++) {
      float a = lrelu(av[h] + adv[h]);
      if (e < CAP1) pl[wid][e * 8 + h] = a;
      m[h] = fmaxf(m[h], a);
    }
    if (e < CAP1) jl[wid][e] = j;
  }
#pragma unroll
  for (int h = 0; h < 8; h++)
#pragma unroll
    for (int off = 32; off > 0; off >>= 1) m[h] = fmaxf(m[h], __shfl_xor(m[h], off));
  // phase B: exp + sum
  float ss[8] = {0.f, 0.f, 0.f, 0.f, 0.f, 0.f, 0.f, 0.f};
  for (int e = lane; e < deg; e += 64) {
    if (e < CAP1) {
#pragma unroll
      for (int h = 0; h < 8; h++) {
        float p = __expf(pl[wid][e * 8 + h] - m[h]);
        pl[wid][e * 8 + h] = p;
        ss[h] += p;
      }
    } else {
      int j = csr_src[beg + e];
      float4 a0 = *(const float4*)&as_[j * 8], a1 = *(const float4*)&as_[j * 8 + 4];
      float av[8] = {a0.x, a0.y, a0.z, a0.w, a1.x, a1.y, a1.z, a1.w};
#pragma unroll
      for (int h = 0; h < 8; h++) ss[h] += __expf(lrelu(av[h] + adv[h]) - m[h]);
    }
  }
#pragma unroll
  for (int h = 0; h < 8; h++)
#pragma unroll
    for (int off = 32; off > 0; off >>= 1) ss[h] += __shfl_xor(ss[h], off);
#pragma unroll
  for (int h = 0; h < 8; h++) {
    float pself = __expf(aself[h] - m[h]);
    float rd = 1.f / (ss[h] + pself + EPSV);
    if (lane == h) {
      sm_m[wid][h] = m[h];
      sm_r[wid][h] = rd;
      sm_p[wid][h] = pself;
    }
  }
  __syncthreads();
  // phase C: half-wave per edge stream; lane owns 4 channels (float4)
  const int sub = lane >> 5, ln = lane & 31;
  const int f0 = ln * 4, hf = ln >> 2;
  const float rdh = sm_r[wid][hf], psh = sm_p[wid][hf], mh = sm_m[wid][hf];
  float4 acc = make_float4(0.f, 0.f, 0.f, 0.f);
  if (sub == 0) {
    float4 hv = *(const float4*)&Hf[(long)ii * 128 + f0];
    acc.x = psh * hv.x;
    acc.y = psh * hv.y;
    acc.z = psh * hv.z;
    acc.w = psh * hv.w;
  }
  if (deg <= CAP1) {
    int e = sub;
    for (; e + 2 < deg; e += 4) {
      int j0 = jl[wid][e], j1 = jl[wid][e + 2];
      float p0 = pl[wid][e * 8 + hf], p1 = pl[wid][(e + 2) * 8 + hf];
      float4 v0 = *(const float4*)&Hf[(long)j0 * 128 + f0];
      float4 v1 = *(const float4*)&Hf[(long)j1 * 128 + f0];
      acc.x += p0 * v0.x + p1 * v1.x;
      acc.y += p0 * v0.y + p1 * v1.y;
      acc.z += p0 * v0.z + p1 * v1.z;
      acc.w += p0 * v0.w + p1 * v1.w;
    }
    for (; e < deg; e += 2) {
      int j = jl[wid][e];
      float p = pl[wid][e * 8 + hf];
      float4 v = *(const float4*)&Hf[(long)j * 128 + f0];
      acc.x += p * v.x;
      acc.y += p * v.y;
      acc.z += p * v.z;
      acc.w += p * v.w;
    }
  } else if (sub == 0) {  // rare fallback
    for (int e = 0; e < deg; e++) {
      int j;
      float p;
      if (e < CAP1) {
        j = jl[wid][e];
        p = pl[wid][e * 8 + hf];
      } else {
        j = csr_src[beg + e];
        p = __expf(lrelu(as_[j * 8 + hf] + adv[hf]) - mh);
      }
      float4 v = *(const float4*)&Hf[(long)j * 128 + f0];
      acc.x += p * v.x;
      acc.y += p * v.y;
      acc.z += p * v.z;
      acc.w += p * v.w;
    }
  }
  acc.x += __shfl_xor(acc.x, 32);
  acc.y += __shfl_xor(acc.y, 32);
  acc.z += __shfl_xor(acc.z, 32);
  acc.w += __shfl_xor(acc.w, 32);
  if (active && sub == 0) {
    float4 b = *(const float4*)&bias[f0];
    float4 o;
    o.x = fmaxf(acc.x * rdh + b.x, 0.f);
    o.y = fmaxf(acc.y * rdh + b.y, 0.f);
    o.z = fmaxf(acc.z * rdh + b.z, 0.f);
    o.w = fmaxf(acc.w * rdh + b.w, 0.f);
    *(float4*)&out[(long)i * 128 + f0] = o;
  }
}

// ---------------- fused per-node softmax+aggregate, layer 2 (H=1,C=64) ----------------
__global__ __launch_bounds__(256) void k_node2(const int* __restrict__ row_ptr,
                                               const int* __restrict__ csr_src,
                                               const float* __restrict__ Hf,
                                               const float* __restrict__ as_,
                                               const float* __restrict__ ad_,
                                               const float* __restrict__ bias,
                                               float* __restrict__ out, int N) {
  __shared__ float pl[4][CAP2];
  __shared__ int jl[4][CAP2];
  const int wid = threadIdx.x >> 6, lane = threadIdx.x & 63;
  const int i = blockIdx.x * 4 + wid;
  const bool active = i < N;
  const int ii = active ? i : (N - 1);
  const int beg = row_ptr[ii];
  const int deg = active ? (row_ptr[ii + 1] - beg) : 0;

  const float adi = ad_[ii];
  const float aself = lrelu(as_[ii] + adi);
  float m = aself;
  for (int e = lane; e < deg; e += 64) {
    int j = csr_src[beg + e];
    float a = lrelu(as_[j] + adi);
    if (e < CAP2) {
      pl[wid][e] = a;
      jl[wid][e] = j;
    }
    m = fmaxf(m, a);
  }
#pragma unroll
  for (int off = 32; off > 0; off >>= 1) m = fmaxf(m, __shfl_xor(m, off));
  float ss = 0.f;
  for (int e = lane; e < deg; e += 64) {
    if (e < CAP2) {
      float p = __expf(pl[wid][e] - m);
      pl[wid][e] = p;
      ss += p;
    } else {
      int j = csr_src[beg + e];
      ss += __expf(lrelu(as_[j] + adi) - m);
    }
  }
#pragma unroll
  for (int off = 32; off > 0; off >>= 1) ss += __shfl_xor(ss, off);
  const float pself = __expf(aself - m);
  const float rd = 1.f / (ss + pself + EPSV);
  __syncthreads();
  // phase C: quarter-wave per edge stream; lane owns 4 channels (float4)
  const int sub = lane >> 4, ln = lane & 15;
  const int f0 = ln * 4;
  float4 acc = make_float4(0.f, 0.f, 0.f, 0.f);
  if (sub == 0) {
    float4 hv = *(const float4*)&Hf[(long)ii * 64 + f0];
    acc.x = pself * hv.x;
    acc.y = pself * hv.y;
    acc.z = pself * hv.z;
    acc.w = pself * hv.w;
  }
  if (deg <= CAP2) {
    int e = sub;
    for (; e + 4 < deg; e += 8) {
      int j0 = jl[wid][e], j1 = jl[wid][e + 4];
      float p0 = pl[wid][e], p1 = pl[wid][e + 4];
      float4 v0 = *(const float4*)&Hf[(long)j0 * 64 + f0];
      float4 v1 = *(const float4*)&Hf[(long)j1 * 64 + f0];
      acc.x += p0 * v0.x + p1 * v1.x;
      acc.y += p0 * v0.y + p1 * v1.y;
      acc.z += p0 * v0.z + p1 * v1.z;
      acc.w += p0 * v0.w + p1 * v1.w;
    }
    for (; e < deg; e += 4) {
      int j = jl[wid][e];
      float p = pl[wid][e];
      float4 v = *(const float4*)&Hf[(long)j * 64 + f0];
      acc.x += p * v.x;
      acc.y += p * v.y;
      acc.z += p * v.z;
      acc.w += p * v.w;
    }
  } else if (sub == 0) {  // rare fallback
    for (int e = 0; e < deg; e++) {
      int j;
      float p;
      if (e < CAP2) {
        j = jl[wid][e];
        p = pl[wid][e];
      } else {
        j = csr_src[beg + e];
        p = __expf(lrelu(as_[j] + adi) - m);
      }
      float4 v = *(const float4*)&Hf[(long)j * 64 + f0];
      acc.x += p * v.x;
      acc.y += p * v.y;
      acc.z += p * v.z;
      acc.w += p * v.w;
    }
  }
#pragma unroll
  for (int off = 16; off <= 32; off <<= 1) {
    acc.x += __shfl_xor(acc.x, off);
    acc.y += __shfl_xor(acc.y, off);
    acc.z += __shfl_xor(acc.z, off);
    acc.w += __shfl_xor(acc.w, off);
  }
  if (active && sub == 0) {
    float4 b = *(const float4*)&bias[f0];
    float4 o;
    o.x = acc.x * rd + b.x;
    o.y = acc.y * rd + b.y;
    o.z = acc.z * rd + b.z;
    o.w = acc.w * rd + b.w;
    *(float4*)&out[(long)i * 64 + f0] = o;
  }
}

extern "C" void kernel_launch(void* const* d_in, const int* in_sizes, int n_in,
                              void* d_out, int out_size, void* d_ws, size_t ws_size,
                              hipStream_t stream) {
  const float* x = (const float*)d_in[0];
  const int* ei = (const int*)d_in[1];
  const float* W1 = (const float*)d_in[2];
  const float* s1 = (const float*)d_in[3];
  const float* dd1 = (const float*)d_in[4];
  const float* b1 = (const float*)d_in[5];
  const float* W2 = (const float*)d_in[6];
  const float* s2 = (const float*)d_in[7];
  const float* dd2 = (const float*)d_in[8];
  const float* b2 = (const float*)d_in[9];
  const int N = in_sizes[0] / 128;
  const int E = in_sizes[1] / 2;
  const int* src = ei;
  const int* dst = ei + E;

  float* wsp = (float*)d_ws;
  float* H1 = wsp;
  float* as1 = H1 + (size_t)N * 128;
  float* ad1 = as1 + (size_t)N * 8;
  float* X2 = ad1 + (size_t)N * 8;
  int* row_ptr = (int*)(X2 + (size_t)N * 128);
  int* csr_src = row_ptr + (N + 1);
  int* bsum = csr_src + E;
  int* cursor = (int*)as1;  // alias: dead before k_att writes as1
  float* out = (float*)d_out;
  float* H2 = H1;
  float* as2 = as1;
  float* ad2 = ad1;

  dim3 B(256);
  auto nb = [](long n) { return dim3((unsigned)((n + 255) / 256)); };
  const int nblk = (N + 1023) / 1024;

  // CSR build (by destination)
  k_zero<<<nb(N), B, 0, stream>>>(cursor, N);
  k_hist<<<nb(E), B, 0, stream>>>(dst, cursor, E);
  k_scan1<<<dim3(nblk), dim3(1024), 0, stream>>>(cursor, row_ptr, bsum, N);
  k_scan2<<<dim3(1), dim3(64), 0, stream>>>(bsum, row_ptr, nblk, N);
  k_scan3<<<nb(N), B, 0, stream>>>(bsum, row_ptr, cursor, N);
  k_scatter<<<nb(E), B, 0, stream>>>(src, dst, cursor, csr_src, E);

  // Layer 1
  k_gemm<128, 128, 16><<<dim3((N + 15) / 16), B, 0, stream>>>(x, W1, H1, N);
  k_att<8, 16><<<nb((long)N * 8), B, 0, stream>>>(H1, s1, dd1, as1, ad1, N);
  k_node1<<<dim3((N + 3) / 4), B, 0, stream>>>(row_ptr, csr_src, H1, as1, ad1, b1, X2, N);

  // Layer 2
  k_gemm<128, 64, 16><<<dim3((N + 15) / 16), B, 0, stream>>>(X2, W2, H2, N);
  k_att<1, 64><<<nb(N), B, 0, stream>>>(H2, s2, dd2, as2, ad2, N);
  k_node2<<<dim3((N + 3) / 4), B, 0, stream>>>(row_ptr, csr_src, H2, as2, ad2, b2, out, N);
}

// Round 6
// 260.131 us; speedup vs baseline: 1.7728x; 1.1808x over previous
//
#include <hip/hip_runtime.h>

#define NEG 0.2f
#define EPSV 1e-16f
#define CAP1 128
#define CAP2 128

typedef _Float16 h4 __attribute__((ext_vector_type(4)));
typedef _Float16 h8 __attribute__((ext_vector_type(8)));

__device__ __forceinline__ float lrelu(float x) { return x > 0.f ? x : NEG * x; }

// ---------------- CSR build ----------------
__global__ void k_zero(int* __restrict__ p, int n) {
  int t = blockIdx.x * 256 + threadIdx.x;
  if (t < n) p[t] = 0;
}
__global__ void k_hist(const int* __restrict__ dst, int* __restrict__ cnt, int E) {
  int t = blockIdx.x * 256 + threadIdx.x;
  if (t < E) atomicAdd(&cnt[dst[t]], 1);
}
__global__ __launch_bounds__(1024) void k_scan1(const int* __restrict__ cnt,
                                                int* __restrict__ row_ptr,
                                                int* __restrict__ bsum, int N) {
  __shared__ int sh[1024];
  int t = blockIdx.x * 1024 + threadIdx.x;
  int v = (t < N) ? cnt[t] : 0;
  sh[threadIdx.x] = v;
  __syncthreads();
  for (int off = 1; off < 1024; off <<= 1) {
    int add = (threadIdx.x >= off) ? sh[threadIdx.x - off] : 0;
    __syncthreads();
    sh[threadIdx.x] += add;
    __syncthreads();
  }
  if (t < N) row_ptr[t] = sh[threadIdx.x] - v;
  if (threadIdx.x == 1023) bsum[blockIdx.x] = sh[1023];
}
__global__ __launch_bounds__(64) void k_scan2(int* __restrict__ bsum,
                                              int* __restrict__ row_ptr, int nb, int N) {
  int tid = threadIdx.x;
  int v = (tid < nb) ? bsum[tid] : 0;
  int inc = v;
#pragma unroll
  for (int off = 1; off < 64; off <<= 1) {
    int u = __shfl_up(inc, off);
    if (tid >= off) inc += u;
  }
  if (tid < nb) bsum[tid] = inc - v;
  if (tid == 63) row_ptr[N] = inc;
}
__global__ void k_scan3(const int* __restrict__ bsum, int* __restrict__ row_ptr,
                        int* __restrict__ cursor, int N) {
  int t = blockIdx.x * 256 + threadIdx.x;
  if (t < N) {
    int v = row_ptr[t] + bsum[t >> 10];
    row_ptr[t] = v;
    cursor[t] = v;
  }
}
__global__ void k_scatter(const int* __restrict__ src, const int* __restrict__ dst,
                          int* __restrict__ cursor, int* __restrict__ csr_src, int E) {
  int t = blockIdx.x * 256 + threadIdx.x;
  if (t >= E) return;
  int i = dst[t];
  int pos = atomicAdd(&cursor[i], 1);
  csr_src[pos] = src[t];
}

// ------- GEMM: Hout[N,M] (fp16) = X[N,K] (fp32) @ W[K,M] -------
template <int K, int M, int R>
__global__ __launch_bounds__(256) void k_gemm(const float* __restrict__ X,
                                              const float* __restrict__ W,
                                              _Float16* __restrict__ Hout, int N) {
  __shared__ float ws[K * M];
  __shared__ float xs[R * K];
  const int tid = threadIdx.x;
  for (int idx = tid * 4; idx < K * M; idx += 1024)
    *(float4*)&ws[idx] = *(const float4*)&W[idx];
  const long row0 = (long)blockIdx.x * R;
  const int nrow = (int)min((long)R, (long)N - row0);
  for (int idx = tid * 4; idx < R * K; idx += 1024) {
    int r = idx / K;
    float4 v = make_float4(0.f, 0.f, 0.f, 0.f);
    if (r < nrow) v = *(const float4*)&X[row0 * K + idx];
    *(float4*)&xs[idx] = v;
  }
  __syncthreads();
  constexpr int NCT = M / 4;
  constexpr int RS = 256 / NCT;
  const int c0 = (tid % NCT) * 4;
  const int rslot = tid / NCT;
  for (int r = rslot; r < R; r += RS) {
    float4 acc = make_float4(0.f, 0.f, 0.f, 0.f);
#pragma unroll
    for (int k = 0; k < K; k += 4) {
      float4 xv = *(float4*)&xs[r * K + k];
      float4 w0 = *(float4*)&ws[(k + 0) * M + c0];
      float4 w1 = *(float4*)&ws[(k + 1) * M + c0];
      float4 w2 = *(float4*)&ws[(k + 2) * M + c0];
      float4 w3 = *(float4*)&ws[(k + 3) * M + c0];
      acc.x += xv.x * w0.x + xv.y * w1.x + xv.z * w2.x + xv.w * w3.x;
      acc.y += xv.x * w0.y + xv.y * w1.y + xv.z * w2.y + xv.w * w3.y;
      acc.z += xv.x * w0.z + xv.y * w1.z + xv.z * w2.z + xv.w * w3.z;
      acc.w += xv.x * w0.w + xv.y * w1.w + xv.z * w2.w + xv.w * w3.w;
    }
    if (r < nrow) {
      h4 o;
      o[0] = (_Float16)acc.x;
      o[1] = (_Float16)acc.y;
      o[2] = (_Float16)acc.z;
      o[3] = (_Float16)acc.w;
      *(h4*)&Hout[(row0 + r) * M + c0] = o;
    }
  }
}

// ---------------- attention dots (fp16 H) ----------------
template <int H, int C>
__global__ void k_att(const _Float16* __restrict__ Hf, const float* __restrict__ atts,
                      const float* __restrict__ attd, float* __restrict__ as_,
                      float* __restrict__ ad_, int N) {
  int t = blockIdx.x * 256 + threadIdx.x;
  if (t >= N * H) return;
  int n = t / H, h = t % H;
  const _Float16* hp = Hf + (long)n * (H * C) + h * C;
  const float* sp = atts + h * C;
  const float* dp = attd + h * C;
  float s = 0.f, d = 0.f;
#pragma unroll
  for (int c = 0; c < C; c += 8) {
    h8 hv = *(const h8*)&hp[c];
#pragma unroll
    for (int q = 0; q < 8; q++) {
      float v = (float)hv[q];
      s += v * sp[c + q];
      d += v * dp[c + q];
    }
  }
  as_[t] = s;
  ad_[t] = d;
}

// ------- fused per-node softmax+aggregate, layer 1 (H=8,C=16), no-max softmax -------
__global__ __launch_bounds__(256) void k_node1(const int* __restrict__ row_ptr,
                                               const int* __restrict__ csr_src,
                                               const _Float16* __restrict__ Hf,
                                               const float* __restrict__ as_,
                                               const float* __restrict__ ad_,
                                               const float* __restrict__ bias,
                                               float* __restrict__ out, int N) {
  __shared__ float pl[4][CAP1 * 8];
  __shared__ int jl[4][CAP1];
  __shared__ float sm_r[4][8], sm_p[4][8];
  const int wid = threadIdx.x >> 6, lane = threadIdx.x & 63;
  const int i = blockIdx.x * 4 + wid;
  const bool active = i < N;
  const int ii = active ? i : (N - 1);
  const int beg = row_ptr[ii];
  const int deg = active ? (row_ptr[ii + 1] - beg) : 0;

  float4 d0 = *(const float4*)&ad_[ii * 8], d1 = *(const float4*)&ad_[ii * 8 + 4];
  float4 s0 = *(const float4*)&as_[ii * 8], s1 = *(const float4*)&as_[ii * 8 + 4];
  float adv[8] = {d0.x, d0.y, d0.z, d0.w, d1.x, d1.y, d1.z, d1.w};
  float asv[8] = {s0.x, s0.y, s0.z, s0.w, s1.x, s1.y, s1.z, s1.w};
  float ps[8];
#pragma unroll
  for (int h = 0; h < 8; h++) ps[h] = __expf(lrelu(asv[h] + adv[h]));
  // phase AB: p = exp(lrelu(alpha)) -> LDS, running sum
  float ss[8] = {0.f, 0.f, 0.f, 0.f, 0.f, 0.f, 0.f, 0.f};
  for (int e = lane; e < deg; e += 64) {
    int j = csr_src[beg + e];
    float4 a0 = *(const float4*)&as_[j * 8], a1 = *(const float4*)&as_[j * 8 + 4];
    float av[8] = {a0.x, a0.y, a0.z, a0.w, a1.x, a1.y, a1.z, a1.w};
    float p[8];
#pragma unroll
    for (int h = 0; h < 8; h++) {
      p[h] = __expf(lrelu(av[h] + adv[h]));
      ss[h] += p[h];
    }
    if (e < CAP1) {
      float4 q0 = make_float4(p[0], p[1], p[2], p[3]);
      float4 q1 = make_float4(p[4], p[5], p[6], p[7]);
      *(float4*)&pl[wid][e * 8] = q0;
      *(float4*)&pl[wid][e * 8 + 4] = q1;
      jl[wid][e] = j;
    }
  }
#pragma unroll
  for (int h = 0; h < 8; h++)
#pragma unroll
    for (int off = 32; off > 0; off >>= 1) ss[h] += __shfl_xor(ss[h], off);
#pragma unroll
  for (int h = 0; h < 8; h++) {
    float rd = 1.f / (ss[h] + ps[h] + EPSV);
    if (lane == h) {
      sm_r[wid][h] = rd;
      sm_p[wid][h] = ps[h];
    }
  }
  __syncthreads();
  // phase C: 4 edge-streams; lane owns 8 channels (16B fp16 loads)
  const int sub = lane >> 4, ln = lane & 15;
  const int f0 = ln * 8, hf = ln >> 1;
  const float rdh = sm_r[wid][hf], psh = sm_p[wid][hf];
  float acc[8] = {0.f, 0.f, 0.f, 0.f, 0.f, 0.f, 0.f, 0.f};
  if (sub == 0) {
    h8 hv = *(const h8*)&Hf[(long)ii * 128 + f0];
#pragma unroll
    for (int c = 0; c < 8; c++) acc[c] = psh * (float)hv[c];
  }
  if (deg <= CAP1) {
    int e = sub;
    for (; e + 4 < deg; e += 8) {
      int j0 = jl[wid][e], j1 = jl[wid][e + 4];
      float p0 = pl[wid][e * 8 + hf], p1 = pl[wid][(e + 4) * 8 + hf];
      h8 v0 = *(const h8*)&Hf[(long)j0 * 128 + f0];
      h8 v1 = *(const h8*)&Hf[(long)j1 * 128 + f0];
#pragma unroll
      for (int c = 0; c < 8; c++) acc[c] += p0 * (float)v0[c] + p1 * (float)v1[c];
    }
    for (; e < deg; e += 4) {
      int j = jl[wid][e];
      float p = pl[wid][e * 8 + hf];
      h8 v = *(const h8*)&Hf[(long)j * 128 + f0];
#pragma unroll
      for (int c = 0; c < 8; c++) acc[c] += p * (float)v[c];
    }
  } else if (sub == 0) {  // rare fallback (deg > CAP1)
    for (int e = 0; e < deg; e++) {
      int j;
      float p;
      if (e < CAP1) {
        j = jl[wid][e];
        p = pl[wid][e * 8 + hf];
      } else {
        j = csr_src[beg + e];
        p = __expf(lrelu(as_[j * 8 + hf] + ad_[ii * 8 + hf]));
      }
      h8 v = *(const h8*)&Hf[(long)j * 128 + f0];
#pragma unroll
      for (int c = 0; c < 8; c++) acc[c] += p * (float)v[c];
    }
  }
#pragma unroll
  for (int c = 0; c < 8; c++) {
    acc[c] += __shfl_xor(acc[c], 16);
    acc[c] += __shfl_xor(acc[c], 32);
  }
  if (active && sub == 0) {
    float4 b0 = *(const float4*)&bias[f0];
    float4 b1 = *(const float4*)&bias[f0 + 4];
    float4 o0, o1;
    o0.x = fmaxf(acc[0] * rdh + b0.x, 0.f);
    o0.y = fmaxf(acc[1] * rdh + b0.y, 0.f);
    o0.z = fmaxf(acc[2] * rdh + b0.z, 0.f);
    o0.w = fmaxf(acc[3] * rdh + b0.w, 0.f);
    o1.x = fmaxf(acc[4] * rdh + b1.x, 0.f);
    o1.y = fmaxf(acc[5] * rdh + b1.y, 0.f);
    o1.z = fmaxf(acc[6] * rdh + b1.z, 0.f);
    o1.w = fmaxf(acc[7] * rdh + b1.w, 0.f);
    *(float4*)&out[(long)i * 128 + f0] = o0;
    *(float4*)&out[(long)i * 128 + f0 + 4] = o1;
  }
}

// ------- fused per-node softmax+aggregate, layer 2 (H=1,C=64), no-max softmax -------
__global__ __launch_bounds__(256) void k_node2(const int* __restrict__ row_ptr,
                                               const int* __restrict__ csr_src,
                                               const _Float16* __restrict__ Hf,
                                               const float* __restrict__ as_,
                                               const float* __restrict__ ad_,
                                               const float* __restrict__ bias,
                                               float* __restrict__ out, int N) {
  __shared__ float pl[4][CAP2];
  __shared__ int jl[4][CAP2];
  const int wid = threadIdx.x >> 6, lane = threadIdx.x & 63;
  const int i = blockIdx.x * 4 + wid;
  const bool active = i < N;
  const int ii = active ? i : (N - 1);
  const int beg = row_ptr[ii];
  const int deg = active ? (row_ptr[ii + 1] - beg) : 0;

  const float adi = ad_[ii];
  const float pself = __expf(lrelu(as_[ii] + adi));
  float ss = 0.f;
  for (int e = lane; e < deg; e += 64) {
    int j = csr_src[beg + e];
    float p = __expf(lrelu(as_[j] + adi));
    if (e < CAP2) {
      pl[wid][e] = p;
      jl[wid][e] = j;
    }
    ss += p;
  }
#pragma unroll
  for (int off = 32; off > 0; off >>= 1) ss += __shfl_xor(ss, off);
  const float rd = 1.f / (ss + pself + EPSV);
  __syncthreads();
  // phase C: 8 edge-streams; lane owns 8 channels (16B fp16 loads)
  const int sub = lane >> 3, ln = lane & 7;
  const int f0 = ln * 8;
  float acc[8] = {0.f, 0.f, 0.f, 0.f, 0.f, 0.f, 0.f, 0.f};
  if (sub == 0) {
    h8 hv = *(const h8*)&Hf[(long)ii * 64 + f0];
#pragma unroll
    for (int c = 0; c < 8; c++) acc[c] = pself * (float)hv[c];
  }
  if (deg <= CAP2) {
    int e = sub;
    for (; e + 8 < deg; e += 16) {
      int j0 = jl[wid][e], j1 = jl[wid][e + 8];
      float p0 = pl[wid][e], p1 = pl[wid][e + 8];
      h8 v0 = *(const h8*)&Hf[(long)j0 * 64 + f0];
      h8 v1 = *(const h8*)&Hf[(long)j1 * 64 + f0];
#pragma unroll
      for (int c = 0; c < 8; c++) acc[c] += p0 * (float)v0[c] + p1 * (float)v1[c];
    }
    for (; e < deg; e += 8) {
      int j = jl[wid][e];
      float p = pl[wid][e];
      h8 v = *(const h8*)&Hf[(long)j * 64 + f0];
#pragma unroll
      for (int c = 0; c < 8; c++) acc[c] += p * (float)v[c];
    }
  } else if (sub == 0) {  // rare fallback
    for (int e = 0; e < deg; e++) {
      int j;
      float p;
      if (e < CAP2) {
        j = jl[wid][e];
        p = pl[wid][e];
      } else {
        j = csr_src[beg + e];
        p = __expf(lrelu(as_[j] + adi));
      }
      h8 v = *(const h8*)&Hf[(long)j * 64 + f0];
#pragma unroll
      for (int c = 0; c < 8; c++) acc[c] += p * (float)v[c];
    }
  }
#pragma unroll
  for (int c = 0; c < 8; c++) {
    acc[c] += __shfl_xor(acc[c], 8);
    acc[c] += __shfl_xor(acc[c], 16);
    acc[c] += __shfl_xor(acc[c], 32);
  }
  if (active && sub == 0) {
    float4 b0 = *(const float4*)&bias[f0];
    float4 b1 = *(const float4*)&bias[f0 + 4];
    float4 o0, o1;
    o0.x = acc[0] * rd + b0.x;
    o0.y = acc[1] * rd + b0.y;
    o0.z = acc[2] * rd + b0.z;
    o0.w = acc[3] * rd + b0.w;
    o1.x = acc[4] * rd + b1.x;
    o1.y = acc[5] * rd + b1.y;
    o1.z = acc[6] * rd + b1.z;
    o1.w = acc[7] * rd + b1.w;
    *(float4*)&out[(long)i * 64 + f0] = o0;
    *(float4*)&out[(long)i * 64 + f0 + 4] = o1;
  }
}

extern "C" void kernel_launch(void* const* d_in, const int* in_sizes, int n_in,
                              void* d_out, int out_size, void* d_ws, size_t ws_size,
                              hipStream_t stream) {
  const float* x = (const float*)d_in[0];
  const int* ei = (const int*)d_in[1];
  const float* W1 = (const float*)d_in[2];
  const float* s1 = (const float*)d_in[3];
  const float* dd1 = (const float*)d_in[4];
  const float* b1 = (const float*)d_in[5];
  const float* W2 = (const float*)d_in[6];
  const float* s2 = (const float*)d_in[7];
  const float* dd2 = (const float*)d_in[8];
  const float* b2 = (const float*)d_in[9];
  const int N = in_sizes[0] / 128;
  const int E = in_sizes[1] / 2;
  const int* src = ei;
  const int* dst = ei + E;

  // ws layout: Hh[N*128 fp16] | as[N*8] | ad[N*8] | X2[N*128] | row_ptr[N+1] | csr_src[E] | bsum[64]
  char* wsp = (char*)d_ws;
  _Float16* Hh = (_Float16*)wsp;
  float* as1 = (float*)(wsp + (size_t)N * 128 * sizeof(_Float16));
  float* ad1 = as1 + (size_t)N * 8;
  float* X2 = ad1 + (size_t)N * 8;
  int* row_ptr = (int*)(X2 + (size_t)N * 128);
  int* csr_src = row_ptr + (N + 1);
  int* bsum = csr_src + E;
  int* cursor = (int*)as1;  // alias: dead before k_att writes as1
  float* out = (float*)d_out;

  dim3 B(256);
  auto nb = [](long n) { return dim3((unsigned)((n + 255) / 256)); };
  const int nblk = (N + 1023) / 1024;

  // CSR build (by destination)
  k_zero<<<nb(N), B, 0, stream>>>(cursor, N);
  k_hist<<<nb(E), B, 0, stream>>>(dst, cursor, E);
  k_scan1<<<dim3(nblk), dim3(1024), 0, stream>>>(cursor, row_ptr, bsum, N);
  k_scan2<<<dim3(1), dim3(64), 0, stream>>>(bsum, row_ptr, nblk, N);
  k_scan3<<<nb(N), B, 0, stream>>>(bsum, row_ptr, cursor, N);
  k_scatter<<<nb(E), B, 0, stream>>>(src, dst, cursor, csr_src, E);

  // Layer 1
  k_gemm<128, 128, 16><<<dim3((N + 15) / 16), B, 0, stream>>>(x, W1, Hh, N);
  k_att<8, 16><<<nb((long)N * 8), B, 0, stream>>>(Hh, s1, dd1, as1, ad1, N);
  k_node1<<<dim3((N + 3) / 4), B, 0, stream>>>(row_ptr, csr_src, Hh, as1, ad1, b1, X2, N);

  // Layer 2 (Hh reused: N*64 fp16 fits in the N*128 slot)
  k_gemm<128, 64, 16><<<dim3((N + 15) / 16), B, 0, stream>>>(X2, W2, Hh, N);
  k_att<1, 64><<<nb(N), B, 0, stream>>>(Hh, s2, dd2, as1, ad1, N);
  k_node2<<<dim3((N + 3) / 4), B, 0, stream>>>(row_ptr, csr_src, Hh, as1, ad1, b2, out, N);
}

// Round 7
// 240.154 us; speedup vs baseline: 1.9203x; 1.0832x over previous
//
#include <hip/hip_runtime.h>

#define NEG 0.2f
#define EPSV 1e-16f
#define CAP1 128
#define CAP2 128

typedef _Float16 h2 __attribute__((ext_vector_type(2)));
typedef _Float16 h4 __attribute__((ext_vector_type(4)));
typedef _Float16 h8 __attribute__((ext_vector_type(8)));

__device__ __forceinline__ float lrelu(float x) { return x > 0.f ? x : NEG * x; }

__device__ __forceinline__ float dot2f(h2 a, h2 b, float c) {
#if __has_builtin(__builtin_amdgcn_fdot2)
  return __builtin_amdgcn_fdot2(a, b, c, false);
#else
  return c + (float)a[0] * (float)b[0] + (float)a[1] * (float)b[1];
#endif
}

// ---------------- CSR build ----------------
__global__ void k_zero(int* __restrict__ p, int n) {
  int t = blockIdx.x * 256 + threadIdx.x;
  if (t < n) p[t] = 0;
}
__global__ void k_hist(const int* __restrict__ dst, int* __restrict__ cnt, int E) {
  int t = blockIdx.x * 256 + threadIdx.x;
  if (t < E) atomicAdd(&cnt[dst[t]], 1);
}
__global__ __launch_bounds__(1024) void k_scan1(const int* __restrict__ cnt,
                                                int* __restrict__ row_ptr,
                                                int* __restrict__ bsum, int N) {
  __shared__ int sh[1024];
  int t = blockIdx.x * 1024 + threadIdx.x;
  int v = (t < N) ? cnt[t] : 0;
  sh[threadIdx.x] = v;
  __syncthreads();
  for (int off = 1; off < 1024; off <<= 1) {
    int add = (threadIdx.x >= off) ? sh[threadIdx.x - off] : 0;
    __syncthreads();
    sh[threadIdx.x] += add;
    __syncthreads();
  }
  if (t < N) row_ptr[t] = sh[threadIdx.x] - v;
  if (threadIdx.x == 1023) bsum[blockIdx.x] = sh[1023];
}
__global__ __launch_bounds__(64) void k_scan2(int* __restrict__ bsum,
                                              int* __restrict__ row_ptr, int nb, int N) {
  int tid = threadIdx.x;
  int v = (tid < nb) ? bsum[tid] : 0;
  int inc = v;
#pragma unroll
  for (int off = 1; off < 64; off <<= 1) {
    int u = __shfl_up(inc, off);
    if (tid >= off) inc += u;
  }
  if (tid < nb) bsum[tid] = inc - v;
  if (tid == 63) row_ptr[N] = inc;
}
__global__ void k_scan3(const int* __restrict__ bsum, int* __restrict__ row_ptr,
                        int* __restrict__ cursor, int N) {
  int t = blockIdx.x * 256 + threadIdx.x;
  if (t < N) {
    int v = row_ptr[t] + bsum[t >> 10];
    row_ptr[t] = v;
    cursor[t] = v;
  }
}
__global__ void k_scatter(const int* __restrict__ src, const int* __restrict__ dst,
                          int* __restrict__ cursor, int* __restrict__ csr_src, int E) {
  int t = blockIdx.x * 256 + threadIdx.x;
  if (t >= E) return;
  int i = dst[t];
  int pos = atomicAdd(&cursor[i], 1);
  csr_src[pos] = src[t];
}

// ------- GEMM via v_dot2_f32_f16: Hout[N,M] (fp16) = X[N,128] (fp32) @ W[128,M] -------
// W staged transposed in fp16 LDS with XOR swizzle; X staged fp16 padded.
template <int M, int R>
__global__ __launch_bounds__(256) void k_gemm_dot(const float* __restrict__ X,
                                                  const float* __restrict__ W,
                                                  _Float16* __restrict__ Hout, int N) {
  constexpr int K = 128;
  constexpr int XS = 136;  // padded fp16 stride for xs
  __shared__ _Float16 wt[M * K];
  __shared__ _Float16 xs[R * XS];
  const int tid = threadIdx.x;
  const long row0 = (long)blockIdx.x * R;
  const int nrow = (int)min((long)R, (long)N - row0);

  // stage W transposed (coalesced global reads over c; swizzled LDS writes)
  for (int idx = tid; idx < (K / 4) * M; idx += 256) {
    int c = idx % M;
    int k0 = (idx / M) * 4;
    h4 o;
    o[0] = (_Float16)W[(k0 + 0) * M + c];
    o[1] = (_Float16)W[(k0 + 1) * M + c];
    o[2] = (_Float16)W[(k0 + 2) * M + c];
    o[3] = (_Float16)W[(k0 + 3) * M + c];
    *(h4*)&wt[c * K + (k0 ^ (4 * (c & 31)))] = o;
  }
  // stage X fp16
  for (int idx = tid; idx < R * (K / 4); idx += 256) {
    int r = idx >> 5;
    int iw = idx & 31;
    float4 v = make_float4(0.f, 0.f, 0.f, 0.f);
    if (r < nrow) v = *(const float4*)&X[(row0 + r) * K + iw * 4];
    h4 o;
    o[0] = (_Float16)v.x;
    o[1] = (_Float16)v.y;
    o[2] = (_Float16)v.z;
    o[3] = (_Float16)v.w;
    *(h4*)&xs[r * XS + iw * 4] = o;
  }
  __syncthreads();

  constexpr int CG = M / 4;           // col groups: 32 (M=128) / 16 (M=64)
  constexpr int RT = (R * CG) / 256;  // rows per thread: 8 / 4
  const int tq = tid % CG;
  const int r0 = (tid / CG) * RT;
  int wbase[4], wmask[4];
#pragma unroll
  for (int q = 0; q < 4; q++) {
    int c = tq + CG * q;
    wbase[q] = c * K;
    wmask[q] = 4 * (c & 31);
  }
  float acc[RT][4];
#pragma unroll
  for (int r = 0; r < RT; r++)
#pragma unroll
    for (int q = 0; q < 4; q++) acc[r][q] = 0.f;

  for (int k = 0; k < K; k += 8) {
    h4 wlo[4], whi[4];
#pragma unroll
    for (int q = 0; q < 4; q++) {
      wlo[q] = *(h4*)&wt[wbase[q] + ((k + 0) ^ wmask[q])];
      whi[q] = *(h4*)&wt[wbase[q] + ((k + 4) ^ wmask[q])];
    }
#pragma unroll
    for (int r = 0; r < RT; r++) {
      h8 xv = *(h8*)&xs[(r0 + r) * XS + k];
      h2 x0 = __builtin_shufflevector(xv, xv, 0, 1);
      h2 x1 = __builtin_shufflevector(xv, xv, 2, 3);
      h2 x2 = __builtin_shufflevector(xv, xv, 4, 5);
      h2 x3 = __builtin_shufflevector(xv, xv, 6, 7);
#pragma unroll
      for (int q = 0; q < 4; q++) {
        h2 w0 = __builtin_shufflevector(wlo[q], wlo[q], 0, 1);
        h2 w1 = __builtin_shufflevector(wlo[q], wlo[q], 2, 3);
        h2 w2 = __builtin_shufflevector(whi[q], whi[q], 0, 1);
        h2 w3 = __builtin_shufflevector(whi[q], whi[q], 2, 3);
        acc[r][q] = dot2f(x0, w0, acc[r][q]);
        acc[r][q] = dot2f(x1, w1, acc[r][q]);
        acc[r][q] = dot2f(x2, w2, acc[r][q]);
        acc[r][q] = dot2f(x3, w3, acc[r][q]);
      }
    }
  }
#pragma unroll
  for (int r = 0; r < RT; r++) {
    if (r0 + r < nrow) {
#pragma unroll
      for (int q = 0; q < 4; q++)
        Hout[(row0 + r0 + r) * M + tq + CG * q] = (_Float16)acc[r][q];
    }
  }
}

// ---------------- attention dots (fp16 H) ----------------
template <int H, int C>
__global__ void k_att(const _Float16* __restrict__ Hf, const float* __restrict__ atts,
                      const float* __restrict__ attd, float* __restrict__ as_,
                      float* __restrict__ ad_, int N) {
  int t = blockIdx.x * 256 + threadIdx.x;
  if (t >= N * H) return;
  int n = t / H, h = t % H;
  const _Float16* hp = Hf + (long)n * (H * C) + h * C;
  const float* sp = atts + h * C;
  const float* dp = attd + h * C;
  float s = 0.f, d = 0.f;
#pragma unroll
  for (int c = 0; c < C; c += 8) {
    h8 hv = *(const h8*)&hp[c];
#pragma unroll
    for (int q = 0; q < 8; q++) {
      float v = (float)hv[q];
      s += v * sp[c + q];
      d += v * dp[c + q];
    }
  }
  as_[t] = s;
  ad_[t] = d;
}

// ------- fused per-node softmax+aggregate, layer 1 (H=8,C=16), no-max softmax -------
__global__ __launch_bounds__(256) void k_node1(const int* __restrict__ row_ptr,
                                               const int* __restrict__ csr_src,
                                               const _Float16* __restrict__ Hf,
                                               const float* __restrict__ as_,
                                               const float* __restrict__ ad_,
                                               const float* __restrict__ bias,
                                               float* __restrict__ out, int N) {
  __shared__ float pl[4][CAP1 * 8];
  __shared__ int jl[4][CAP1];
  __shared__ float sm_r[4][8], sm_p[4][8];
  const int wid = threadIdx.x >> 6, lane = threadIdx.x & 63;
  const int i = blockIdx.x * 4 + wid;
  const bool active = i < N;
  const int ii = active ? i : (N - 1);
  const int beg = row_ptr[ii];
  const int deg = active ? (row_ptr[ii + 1] - beg) : 0;

  float4 d0 = *(const float4*)&ad_[ii * 8], d1 = *(const float4*)&ad_[ii * 8 + 4];
  float4 s0 = *(const float4*)&as_[ii * 8], s1 = *(const float4*)&as_[ii * 8 + 4];
  float adv[8] = {d0.x, d0.y, d0.z, d0.w, d1.x, d1.y, d1.z, d1.w};
  float asv[8] = {s0.x, s0.y, s0.z, s0.w, s1.x, s1.y, s1.z, s1.w};
  float ps[8];
#pragma unroll
  for (int h = 0; h < 8; h++) ps[h] = __expf(lrelu(asv[h] + adv[h]));
  float ss[8] = {0.f, 0.f, 0.f, 0.f, 0.f, 0.f, 0.f, 0.f};
  for (int e = lane; e < deg; e += 64) {
    int j = csr_src[beg + e];
    float4 a0 = *(const float4*)&as_[j * 8], a1 = *(const float4*)&as_[j * 8 + 4];
    float av[8] = {a0.x, a0.y, a0.z, a0.w, a1.x, a1.y, a1.z, a1.w};
    float p[8];
#pragma unroll
    for (int h = 0; h < 8; h++) {
      p[h] = __expf(lrelu(av[h] + adv[h]));
      ss[h] += p[h];
    }
    if (e < CAP1) {
      float4 q0 = make_float4(p[0], p[1], p[2], p[3]);
      float4 q1 = make_float4(p[4], p[5], p[6], p[7]);
      *(float4*)&pl[wid][e * 8] = q0;
      *(float4*)&pl[wid][e * 8 + 4] = q1;
      jl[wid][e] = j;
    }
  }
#pragma unroll
  for (int h = 0; h < 8; h++)
#pragma unroll
    for (int off = 32; off > 0; off >>= 1) ss[h] += __shfl_xor(ss[h], off);
#pragma unroll
  for (int h = 0; h < 8; h++) {
    float rd = 1.f / (ss[h] + ps[h] + EPSV);
    if (lane == h) {
      sm_r[wid][h] = rd;
      sm_p[wid][h] = ps[h];
    }
  }
  __syncthreads();
  const int sub = lane >> 4, ln = lane & 15;
  const int f0 = ln * 8, hf = ln >> 1;
  const float rdh = sm_r[wid][hf], psh = sm_p[wid][hf];
  float acc[8] = {0.f, 0.f, 0.f, 0.f, 0.f, 0.f, 0.f, 0.f};
  if (sub == 0) {
    h8 hv = *(const h8*)&Hf[(long)ii * 128 + f0];
#pragma unroll
    for (int c = 0; c < 8; c++) acc[c] = psh * (float)hv[c];
  }
  if (deg <= CAP1) {
    int e = sub;
    for (; e + 4 < deg; e += 8) {
      int j0 = jl[wid][e], j1 = jl[wid][e + 4];
      float p0 = pl[wid][e * 8 + hf], p1 = pl[wid][(e + 4) * 8 + hf];
      h8 v0 = *(const h8*)&Hf[(long)j0 * 128 + f0];
      h8 v1 = *(const h8*)&Hf[(long)j1 * 128 + f0];
#pragma unroll
      for (int c = 0; c < 8; c++) acc[c] += p0 * (float)v0[c] + p1 * (float)v1[c];
    }
    for (; e < deg; e += 4) {
      int j = jl[wid][e];
      float p = pl[wid][e * 8 + hf];
      h8 v = *(const h8*)&Hf[(long)j * 128 + f0];
#pragma unroll
      for (int c = 0; c < 8; c++) acc[c] += p * (float)v[c];
    }
  } else if (sub == 0) {  // rare fallback (deg > CAP1)
    for (int e = 0; e < deg; e++) {
      int j;
      float p;
      if (e < CAP1) {
        j = jl[wid][e];
        p = pl[wid][e * 8 + hf];
      } else {
        j = csr_src[beg + e];
        p = __expf(lrelu(as_[j * 8 + hf] + ad_[ii * 8 + hf]));
      }
      h8 v = *(const h8*)&Hf[(long)j * 128 + f0];
#pragma unroll
      for (int c = 0; c < 8; c++) acc[c] += p * (float)v[c];
    }
  }
#pragma unroll
  for (int c = 0; c < 8; c++) {
    acc[c] += __shfl_xor(acc[c], 16);
    acc[c] += __shfl_xor(acc[c], 32);
  }
  if (active && sub == 0) {
    float4 b0 = *(const float4*)&bias[f0];
    float4 b1 = *(const float4*)&bias[f0 + 4];
    float4 o0, o1;
    o0.x = fmaxf(acc[0] * rdh + b0.x, 0.f);
    o0.y = fmaxf(acc[1] * rdh + b0.y, 0.f);
    o0.z = fmaxf(acc[2] * rdh + b0.z, 0.f);
    o0.w = fmaxf(acc[3] * rdh + b0.w, 0.f);
    o1.x = fmaxf(acc[4] * rdh + b1.x, 0.f);
    o1.y = fmaxf(acc[5] * rdh + b1.y, 0.f);
    o1.z = fmaxf(acc[6] * rdh + b1.z, 0.f);
    o1.w = fmaxf(acc[7] * rdh + b1.w, 0.f);
    *(float4*)&out[(long)i * 128 + f0] = o0;
    *(float4*)&out[(long)i * 128 + f0 + 4] = o1;
  }
}

// ------- fused per-node softmax+aggregate, layer 2 (H=1,C=64), no-max softmax -------
__global__ __launch_bounds__(256) void k_node2(const int* __restrict__ row_ptr,
                                               const int* __restrict__ csr_src,
                                               const _Float16* __restrict__ Hf,
                                               const float* __restrict__ as_,
                                               const float* __restrict__ ad_,
                                               const float* __restrict__ bias,
                                               float* __restrict__ out, int N) {
  __shared__ float pl[4][CAP2];
  __shared__ int jl[4][CAP2];
  const int wid = threadIdx.x >> 6, lane = threadIdx.x & 63;
  const int i = blockIdx.x * 4 + wid;
  const bool active = i < N;
  const int ii = active ? i : (N - 1);
  const int beg = row_ptr[ii];
  const int deg = active ? (row_ptr[ii + 1] - beg) : 0;

  const float adi = ad_[ii];
  const float pself = __expf(lrelu(as_[ii] + adi));
  float ss = 0.f;
  for (int e = lane; e < deg; e += 64) {
    int j = csr_src[beg + e];
    float p = __expf(lrelu(as_[j] + adi));
    if (e < CAP2) {
      pl[wid][e] = p;
      jl[wid][e] = j;
    }
    ss += p;
  }
#pragma unroll
  for (int off = 32; off > 0; off >>= 1) ss += __shfl_xor(ss, off);
  const float rd = 1.f / (ss + pself + EPSV);
  __syncthreads();
  const int sub = lane >> 3, ln = lane & 7;
  const int f0 = ln * 8;
  float acc[8] = {0.f, 0.f, 0.f, 0.f, 0.f, 0.f, 0.f, 0.f};
  if (sub == 0) {
    h8 hv = *(const h8*)&Hf[(long)ii * 64 + f0];
#pragma unroll
    for (int c = 0; c < 8; c++) acc[c] = pself * (float)hv[c];
  }
  if (deg <= CAP2) {
    int e = sub;
    for (; e + 8 < deg; e += 16) {
      int j0 = jl[wid][e], j1 = jl[wid][e + 8];
      float p0 = pl[wid][e], p1 = pl[wid][e + 8];
      h8 v0 = *(const h8*)&Hf[(long)j0 * 64 + f0];
      h8 v1 = *(const h8*)&Hf[(long)j1 * 64 + f0];
#pragma unroll
      for (int c = 0; c < 8; c++) acc[c] += p0 * (float)v0[c] + p1 * (float)v1[c];
    }
    for (; e < deg; e += 8) {
      int j = jl[wid][e];
      float p = pl[wid][e];
      h8 v = *(const h8*)&Hf[(long)j * 64 + f0];
#pragma unroll
      for (int c = 0; c < 8; c++) acc[c] += p * (float)v[c];
    }
  } else if (sub == 0) {  // rare fallback
    for (int e = 0; e < deg; e++) {
      int j;
      float p;
      if (e < CAP2) {
        j = jl[wid][e];
        p = pl[wid][e];
      } else {
        j = csr_src[beg + e];
        p = __expf(lrelu(as_[j] + adi));
      }
      h8 v = *(const h8*)&Hf[(long)j * 64 + f0];
#pragma unroll
      for (int c = 0; c < 8; c++) acc[c] += p * (float)v[c];
    }
  }
#pragma unroll
  for (int c = 0; c < 8; c++) {
    acc[c] += __shfl_xor(acc[c], 8);
    acc[c] += __shfl_xor(acc[c], 16);
    acc[c] += __shfl_xor(acc[c], 32);
  }
  if (active && sub == 0) {
    float4 b0 = *(const float4*)&bias[f0];
    float4 b1 = *(const float4*)&bias[f0 + 4];
    float4 o0, o1;
    o0.x = acc[0] * rd + b0.x;
    o0.y = acc[1] * rd + b0.y;
    o0.z = acc[2] * rd + b0.z;
    o0.w = acc[3] * rd + b0.w;
    o1.x = acc[4] * rd + b1.x;
    o1.y = acc[5] * rd + b1.y;
    o1.z = acc[6] * rd + b1.z;
    o1.w = acc[7] * rd + b1.w;
    *(float4*)&out[(long)i * 64 + f0] = o0;
    *(float4*)&out[(long)i * 64 + f0 + 4] = o1;
  }
}

extern "C" void kernel_launch(void* const* d_in, const int* in_sizes, int n_in,
                              void* d_out, int out_size, void* d_ws, size_t ws_size,
                              hipStream_t stream) {
  const float* x = (const float*)d_in[0];
  const int* ei = (const int*)d_in[1];
  const float* W1 = (const float*)d_in[2];
  const float* s1 = (const float*)d_in[3];
  const float* dd1 = (const float*)d_in[4];
  const float* b1 = (const float*)d_in[5];
  const float* W2 = (const float*)d_in[6];
  const float* s2 = (const float*)d_in[7];
  const float* dd2 = (const float*)d_in[8];
  const float* b2 = (const float*)d_in[9];
  const int N = in_sizes[0] / 128;
  const int E = in_sizes[1] / 2;
  const int* src = ei;
  const int* dst = ei + E;

  // ws layout: Hh[N*128 fp16] | as[N*8] | ad[N*8] | X2[N*128] | row_ptr[N+1] | csr_src[E] | bsum[64]
  char* wsp = (char*)d_ws;
  _Float16* Hh = (_Float16*)wsp;
  float* as1 = (float*)(wsp + (size_t)N * 128 * sizeof(_Float16));
  float* ad1 = as1 + (size_t)N * 8;
  float* X2 = ad1 + (size_t)N * 8;
  int* row_ptr = (int*)(X2 + (size_t)N * 128);
  int* csr_src = row_ptr + (N + 1);
  int* bsum = csr_src + E;
  int* cursor = (int*)as1;  // alias: dead before k_att writes as1
  float* out = (float*)d_out;

  dim3 B(256);
  auto nb = [](long n) { return dim3((unsigned)((n + 255) / 256)); };
  const int nblk = (N + 1023) / 1024;

  // CSR build (by destination)
  k_zero<<<nb(N), B, 0, stream>>>(cursor, N);
  k_hist<<<nb(E), B, 0, stream>>>(dst, cursor, E);
  k_scan1<<<dim3(nblk), dim3(1024), 0, stream>>>(cursor, row_ptr, bsum, N);
  k_scan2<<<dim3(1), dim3(64), 0, stream>>>(bsum, row_ptr, nblk, N);
  k_scan3<<<nb(N), B, 0, stream>>>(bsum, row_ptr, cursor, N);
  k_scatter<<<nb(E), B, 0, stream>>>(src, dst, cursor, csr_src, E);

  // Layer 1
  k_gemm_dot<128, 64><<<dim3((N + 63) / 64), B, 0, stream>>>(x, W1, Hh, N);
  k_att<8, 16><<<nb((long)N * 8), B, 0, stream>>>(Hh, s1, dd1, as1, ad1, N);
  k_node1<<<dim3((N + 3) / 4), B, 0, stream>>>(row_ptr, csr_src, Hh, as1, ad1, b1, X2, N);

  // Layer 2 (Hh reused: N*64 fp16 fits in the N*128 slot)
  k_gemm_dot<64, 64><<<dim3((N + 63) / 64), B, 0, stream>>>(X2, W2, Hh, N);
  k_att<1, 64><<<nb(N), B, 0, stream>>>(Hh, s2, dd2, as1, ad1, N);
  k_node2<<<dim3((N + 3) / 4), B, 0, stream>>>(row_ptr, csr_src, Hh, as1, ad1, b2, out, N);
}

// Round 8
// 220.066 us; speedup vs baseline: 2.0956x; 1.0913x over previous
//
#include <hip/hip_runtime.h>

#define NEG 0.2f
#define EPSV 1e-16f

typedef _Float16 h2 __attribute__((ext_vector_type(2)));
typedef _Float16 h4 __attribute__((ext_vector_type(4)));
typedef _Float16 h8 __attribute__((ext_vector_type(8)));

__device__ __forceinline__ float lrelu(float x) { return x > 0.f ? x : NEG * x; }

__device__ __forceinline__ float dot2f(h2 a, h2 b, float c) {
#if __has_builtin(__builtin_amdgcn_fdot2)
  return __builtin_amdgcn_fdot2(a, b, c, false);
#else
  return c + (float)a[0] * (float)b[0] + (float)a[1] * (float)b[1];
#endif
}

// ---------------- CSR build ----------------
__global__ void k_zero(int* __restrict__ p, int n) {
  int t = blockIdx.x * 256 + threadIdx.x;
  if (t < n) p[t] = 0;
}
__global__ void k_hist(const int* __restrict__ dst, int* __restrict__ cnt, int E) {
  int t = blockIdx.x * 256 + threadIdx.x;
  if (t < E) atomicAdd(&cnt[dst[t]], 1);
}
__global__ __launch_bounds__(1024) void k_scan1(const int* __restrict__ cnt,
                                                int* __restrict__ row_ptr,
                                                int* __restrict__ bsum, int N) {
  __shared__ int sh[1024];
  int t = blockIdx.x * 1024 + threadIdx.x;
  int v = (t < N) ? cnt[t] : 0;
  sh[threadIdx.x] = v;
  __syncthreads();
  for (int off = 1; off < 1024; off <<= 1) {
    int add = (threadIdx.x >= off) ? sh[threadIdx.x - off] : 0;
    __syncthreads();
    sh[threadIdx.x] += add;
    __syncthreads();
  }
  if (t < N) row_ptr[t] = sh[threadIdx.x] - v;
  if (threadIdx.x == 1023) bsum[blockIdx.x] = sh[1023];
}
__global__ __launch_bounds__(64) void k_scan2(int* __restrict__ bsum,
                                              int* __restrict__ row_ptr, int nb, int N) {
  int tid = threadIdx.x;
  int v = (tid < nb) ? bsum[tid] : 0;
  int inc = v;
#pragma unroll
  for (int off = 1; off < 64; off <<= 1) {
    int u = __shfl_up(inc, off);
    if (tid >= off) inc += u;
  }
  if (tid < nb) bsum[tid] = inc - v;
  if (tid == 63) row_ptr[N] = inc;
}
__global__ void k_scan3(const int* __restrict__ bsum, int* __restrict__ row_ptr,
                        int* __restrict__ cursor, int N) {
  int t = blockIdx.x * 256 + threadIdx.x;
  if (t < N) {
    int v = row_ptr[t] + bsum[t >> 10];
    row_ptr[t] = v;
    cursor[t] = v;
  }
}
__global__ void k_scatter(const int* __restrict__ src, const int* __restrict__ dst,
                          int* __restrict__ cursor, int* __restrict__ csr_src, int E) {
  int t = blockIdx.x * 256 + threadIdx.x;
  if (t >= E) return;
  int i = dst[t];
  int pos = atomicAdd(&cursor[i], 1);
  csr_src[pos] = src[t];
}

// ------- GEMM via v_dot2_f32_f16: Hout[N,M] (fp16) = X[N,128] (fp32) @ W[128,M] -------
template <int M, int R>
__global__ __launch_bounds__(256) void k_gemm_dot(const float* __restrict__ X,
                                                  const float* __restrict__ W,
                                                  _Float16* __restrict__ Hout, int N) {
  constexpr int K = 128;
  constexpr int XS = 136;
  __shared__ _Float16 wt[M * K];
  __shared__ _Float16 xs[R * XS];
  const int tid = threadIdx.x;
  const long row0 = (long)blockIdx.x * R;
  const int nrow = (int)min((long)R, (long)N - row0);

  for (int idx = tid; idx < (K / 4) * M; idx += 256) {
    int c = idx % M;
    int k0 = (idx / M) * 4;
    h4 o;
    o[0] = (_Float16)W[(k0 + 0) * M + c];
    o[1] = (_Float16)W[(k0 + 1) * M + c];
    o[2] = (_Float16)W[(k0 + 2) * M + c];
    o[3] = (_Float16)W[(k0 + 3) * M + c];
    *(h4*)&wt[c * K + (k0 ^ (4 * (c & 31)))] = o;
  }
  for (int idx = tid; idx < R * (K / 4); idx += 256) {
    int r = idx >> 5;
    int iw = idx & 31;
    float4 v = make_float4(0.f, 0.f, 0.f, 0.f);
    if (r < nrow) v = *(const float4*)&X[(row0 + r) * K + iw * 4];
    h4 o;
    o[0] = (_Float16)v.x;
    o[1] = (_Float16)v.y;
    o[2] = (_Float16)v.z;
    o[3] = (_Float16)v.w;
    *(h4*)&xs[r * XS + iw * 4] = o;
  }
  __syncthreads();

  constexpr int CG = M / 4;
  constexpr int RT = (R * CG) / 256;
  const int tq = tid % CG;
  const int r0 = (tid / CG) * RT;
  int wbase[4], wmask[4];
#pragma unroll
  for (int q = 0; q < 4; q++) {
    int c = tq + CG * q;
    wbase[q] = c * K;
    wmask[q] = 4 * (c & 31);
  }
  float acc[RT][4];
#pragma unroll
  for (int r = 0; r < RT; r++)
#pragma unroll
    for (int q = 0; q < 4; q++) acc[r][q] = 0.f;

  for (int k = 0; k < K; k += 8) {
    h4 wlo[4], whi[4];
#pragma unroll
    for (int q = 0; q < 4; q++) {
      wlo[q] = *(h4*)&wt[wbase[q] + ((k + 0) ^ wmask[q])];
      whi[q] = *(h4*)&wt[wbase[q] + ((k + 4) ^ wmask[q])];
    }
#pragma unroll
    for (int r = 0; r < RT; r++) {
      h8 xv = *(h8*)&xs[(r0 + r) * XS + k];
      h2 x0 = __builtin_shufflevector(xv, xv, 0, 1);
      h2 x1 = __builtin_shufflevector(xv, xv, 2, 3);
      h2 x2 = __builtin_shufflevector(xv, xv, 4, 5);
      h2 x3 = __builtin_shufflevector(xv, xv, 6, 7);
#pragma unroll
      for (int q = 0; q < 4; q++) {
        h2 w0 = __builtin_shufflevector(wlo[q], wlo[q], 0, 1);
        h2 w1 = __builtin_shufflevector(wlo[q], wlo[q], 2, 3);
        h2 w2 = __builtin_shufflevector(whi[q], whi[q], 0, 1);
        h2 w3 = __builtin_shufflevector(whi[q], whi[q], 2, 3);
        acc[r][q] = dot2f(x0, w0, acc[r][q]);
        acc[r][q] = dot2f(x1, w1, acc[r][q]);
        acc[r][q] = dot2f(x2, w2, acc[r][q]);
        acc[r][q] = dot2f(x3, w3, acc[r][q]);
      }
    }
  }
#pragma unroll
  for (int r = 0; r < RT; r++) {
    if (r0 + r < nrow) {
#pragma unroll
      for (int q = 0; q < 4; q++)
        Hout[(row0 + r0 + r) * M + tq + CG * q] = (_Float16)acc[r][q];
    }
  }
}

// ---------------- attention dots (fp16 H) ----------------
template <int H, int C>
__global__ void k_att(const _Float16* __restrict__ Hf, const float* __restrict__ atts,
                      const float* __restrict__ attd, float* __restrict__ as_,
                      float* __restrict__ ad_, int N) {
  int t = blockIdx.x * 256 + threadIdx.x;
  if (t >= N * H) return;
  int n = t / H, h = t % H;
  const _Float16* hp = Hf + (long)n * (H * C) + h * C;
  const float* sp = atts + h * C;
  const float* dp = attd + h * C;
  float s = 0.f, d = 0.f;
#pragma unroll
  for (int c = 0; c < C; c += 8) {
    h8 hv = *(const h8*)&hp[c];
#pragma unroll
    for (int q = 0; q < 8; q++) {
      float v = (float)hv[q];
      s += v * sp[c + q];
      d += v * dp[c + q];
    }
  }
  as_[t] = s;
  ad_[t] = d;
}

// ------- single-pass per-node softmax+aggregate, layer 1 (H=8,C=16) -------
// 4 subgroups of 16 lanes; lane owns 8 channels (f0..f0+7), head hf = ln>>1.
// No LDS, no barriers: p recomputed inline; denominator applied at the end.
__global__ __launch_bounds__(256) void k_node1(const int* __restrict__ row_ptr,
                                               const int* __restrict__ csr_src,
                                               const _Float16* __restrict__ Hf,
                                               const float* __restrict__ as_,
                                               const float* __restrict__ ad_,
                                               const float* __restrict__ bias,
                                               float* __restrict__ out, int N) {
  const int wid = threadIdx.x >> 6, lane = threadIdx.x & 63;
  const int i = blockIdx.x * 4 + wid;
  if (i >= N) return;
  const int beg = row_ptr[i];
  const int deg = row_ptr[i + 1] - beg;
  const int sub = lane >> 4, ln = lane & 15;
  const int f0 = ln * 8, hf = ln >> 1;

  const float adh = ad_[i * 8 + hf];
  const float pself = __expf(lrelu(as_[i * 8 + hf] + adh));
  float acc[8] = {0.f, 0.f, 0.f, 0.f, 0.f, 0.f, 0.f, 0.f};
  float sp = 0.f;

  int e = sub;
  for (; e + 4 < deg; e += 8) {
    int j0 = csr_src[beg + e], j1 = csr_src[beg + e + 4];
    float p0 = __expf(lrelu(as_[j0 * 8 + hf] + adh));
    float p1 = __expf(lrelu(as_[j1 * 8 + hf] + adh));
    h8 v0 = *(const h8*)&Hf[(long)j0 * 128 + f0];
    h8 v1 = *(const h8*)&Hf[(long)j1 * 128 + f0];
    sp += p0 + p1;
#pragma unroll
    for (int c = 0; c < 8; c++) acc[c] += p0 * (float)v0[c] + p1 * (float)v1[c];
  }
  for (; e < deg; e += 4) {
    int j = csr_src[beg + e];
    float p = __expf(lrelu(as_[j * 8 + hf] + adh));
    h8 v = *(const h8*)&Hf[(long)j * 128 + f0];
    sp += p;
#pragma unroll
    for (int c = 0; c < 8; c++) acc[c] += p * (float)v[c];
  }
  if (sub == 0) {
    h8 hv = *(const h8*)&Hf[(long)i * 128 + f0];
#pragma unroll
    for (int c = 0; c < 8; c++) acc[c] += pself * (float)hv[c];
  }
  // denominator: sum subgroup partials (subgroups own disjoint edge sets)
  sp += __shfl_xor(sp, 16);
  sp += __shfl_xor(sp, 32);
  const float rd = 1.f / (sp + pself + EPSV);
  // channel accumulators across subgroups
#pragma unroll
  for (int c = 0; c < 8; c++) {
    acc[c] += __shfl_xor(acc[c], 16);
    acc[c] += __shfl_xor(acc[c], 32);
  }
  if (sub == 0) {
    float4 b0 = *(const float4*)&bias[f0];
    float4 b1 = *(const float4*)&bias[f0 + 4];
    float4 o0, o1;
    o0.x = fmaxf(acc[0] * rd + b0.x, 0.f);
    o0.y = fmaxf(acc[1] * rd + b0.y, 0.f);
    o0.z = fmaxf(acc[2] * rd + b0.z, 0.f);
    o0.w = fmaxf(acc[3] * rd + b0.w, 0.f);
    o1.x = fmaxf(acc[4] * rd + b1.x, 0.f);
    o1.y = fmaxf(acc[5] * rd + b1.y, 0.f);
    o1.z = fmaxf(acc[6] * rd + b1.z, 0.f);
    o1.w = fmaxf(acc[7] * rd + b1.w, 0.f);
    *(float4*)&out[(long)i * 128 + f0] = o0;
    *(float4*)&out[(long)i * 128 + f0 + 4] = o1;
  }
}

// ------- single-pass per-node softmax+aggregate, layer 2 (H=1,C=64) -------
// 8 subgroups of 8 lanes; lane owns 8 channels.
__global__ __launch_bounds__(256) void k_node2(const int* __restrict__ row_ptr,
                                               const int* __restrict__ csr_src,
                                               const _Float16* __restrict__ Hf,
                                               const float* __restrict__ as_,
                                               const float* __restrict__ ad_,
                                               const float* __restrict__ bias,
                                               float* __restrict__ out, int N) {
  const int wid = threadIdx.x >> 6, lane = threadIdx.x & 63;
  const int i = blockIdx.x * 4 + wid;
  if (i >= N) return;
  const int beg = row_ptr[i];
  const int deg = row_ptr[i + 1] - beg;
  const int sub = lane >> 3, ln = lane & 7;
  const int f0 = ln * 8;

  const float adi = ad_[i];
  const float pself = __expf(lrelu(as_[i] + adi));
  float acc[8] = {0.f, 0.f, 0.f, 0.f, 0.f, 0.f, 0.f, 0.f};
  float sp = 0.f;

  int e = sub;
  for (; e + 8 < deg; e += 16) {
    int j0 = csr_src[beg + e], j1 = csr_src[beg + e + 8];
    float p0 = __expf(lrelu(as_[j0] + adi));
    float p1 = __expf(lrelu(as_[j1] + adi));
    h8 v0 = *(const h8*)&Hf[(long)j0 * 64 + f0];
    h8 v1 = *(const h8*)&Hf[(long)j1 * 64 + f0];
    sp += p0 + p1;
#pragma unroll
    for (int c = 0; c < 8; c++) acc[c] += p0 * (float)v0[c] + p1 * (float)v1[c];
  }
  for (; e < deg; e += 8) {
    int j = csr_src[beg + e];
    float p = __expf(lrelu(as_[j] + adi));
    h8 v = *(const h8*)&Hf[(long)j * 64 + f0];
    sp += p;
#pragma unroll
    for (int c = 0; c < 8; c++) acc[c] += p * (float)v[c];
  }
  if (sub == 0) {
    h8 hv = *(const h8*)&Hf[(long)i * 64 + f0];
#pragma unroll
    for (int c = 0; c < 8; c++) acc[c] += pself * (float)hv[c];
  }
  sp += __shfl_xor(sp, 8);
  sp += __shfl_xor(sp, 16);
  sp += __shfl_xor(sp, 32);
  const float rd = 1.f / (sp + pself + EPSV);
#pragma unroll
  for (int c = 0; c < 8; c++) {
    acc[c] += __shfl_xor(acc[c], 8);
    acc[c] += __shfl_xor(acc[c], 16);
    acc[c] += __shfl_xor(acc[c], 32);
  }
  if (sub == 0) {
    float4 b0 = *(const float4*)&bias[f0];
    float4 b1 = *(const float4*)&bias[f0 + 4];
    float4 o0, o1;
    o0.x = acc[0] * rd + b0.x;
    o0.y = acc[1] * rd + b0.y;
    o0.z = acc[2] * rd + b0.z;
    o0.w = acc[3] * rd + b0.w;
    o1.x = acc[4] * rd + b1.x;
    o1.y = acc[5] * rd + b1.y;
    o1.z = acc[6] * rd + b1.z;
    o1.w = acc[7] * rd + b1.w;
    *(float4*)&out[(long)i * 64 + f0] = o0;
    *(float4*)&out[(long)i * 64 + f0 + 4] = o1;
  }
}

extern "C" void kernel_launch(void* const* d_in, const int* in_sizes, int n_in,
                              void* d_out, int out_size, void* d_ws, size_t ws_size,
                              hipStream_t stream) {
  const float* x = (const float*)d_in[0];
  const int* ei = (const int*)d_in[1];
  const float* W1 = (const float*)d_in[2];
  const float* s1 = (const float*)d_in[3];
  const float* dd1 = (const float*)d_in[4];
  const float* b1 = (const float*)d_in[5];
  const float* W2 = (const float*)d_in[6];
  const float* s2 = (const float*)d_in[7];
  const float* dd2 = (const float*)d_in[8];
  const float* b2 = (const float*)d_in[9];
  const int N = in_sizes[0] / 128;
  const int E = in_sizes[1] / 2;
  const int* src = ei;
  const int* dst = ei + E;

  // ws layout: Hh[N*128 fp16] | as[N*8] | ad[N*8] | X2[N*128] | row_ptr[N+1] | csr_src[E] | bsum[64]
  char* wsp = (char*)d_ws;
  _Float16* Hh = (_Float16*)wsp;
  float* as1 = (float*)(wsp + (size_t)N * 128 * sizeof(_Float16));
  float* ad1 = as1 + (size_t)N * 8;
  float* X2 = ad1 + (size_t)N * 8;
  int* row_ptr = (int*)(X2 + (size_t)N * 128);
  int* csr_src = row_ptr + (N + 1);
  int* bsum = csr_src + E;
  int* cursor = (int*)as1;  // alias: dead before k_att writes as1
  float* out = (float*)d_out;

  dim3 B(256);
  auto nb = [](long n) { return dim3((unsigned)((n + 255) / 256)); };
  const int nblk = (N + 1023) / 1024;

  // CSR build (by destination)
  k_zero<<<nb(N), B, 0, stream>>>(cursor, N);
  k_hist<<<nb(E), B, 0, stream>>>(dst, cursor, E);
  k_scan1<<<dim3(nblk), dim3(1024), 0, stream>>>(cursor, row_ptr, bsum, N);
  k_scan2<<<dim3(1), dim3(64), 0, stream>>>(bsum, row_ptr, nblk, N);
  k_scan3<<<nb(N), B, 0, stream>>>(bsum, row_ptr, cursor, N);
  k_scatter<<<nb(E), B, 0, stream>>>(src, dst, cursor, csr_src, E);

  // Layer 1
  k_gemm_dot<128, 64><<<dim3((N + 63) / 64), B, 0, stream>>>(x, W1, Hh, N);
  k_att<8, 16><<<nb((long)N * 8), B, 0, stream>>>(Hh, s1, dd1, as1, ad1, N);
  k_node1<<<dim3((N + 3) / 4), B, 0, stream>>>(row_ptr, csr_src, Hh, as1, ad1, b1, X2, N);

  // Layer 2 (Hh reused: N*64 fp16 fits in the N*128 slot)
  k_gemm_dot<64, 64><<<dim3((N + 63) / 64), B, 0, stream>>>(X2, W2, Hh, N);
  k_att<1, 64><<<nb(N), B, 0, stream>>>(Hh, s2, dd2, as1, ad1, N);
  k_node2<<<dim3((N + 3) / 4), B, 0, stream>>>(row_ptr, csr_src, Hh, as1, ad1, b2, out, N);
}